// Round 4
// baseline (232.959 us; speedup 1.0000x reference)
//
#include <hip/hip_runtime.h>
#include <hip/hip_fp16.h>

// Problem constants (reference: N_HEAD=8, D_IN=128, D_KEY=32, B=65536)
#define TEMP_INV 0.17677669529663687f

typedef _Float16 f16x8 __attribute__((ext_vector_type(8)));
typedef float    f32x4 __attribute__((ext_vector_type(4)));

__device__ __forceinline__ ushort f2h(float x){
  __half h = __float2half(x);
  return __half_as_ushort(h);
}
__device__ __forceinline__ ushort4 f4h(float4 v){
  ushort4 o; o.x=f2h(v.x); o.y=f2h(v.y); o.z=f2h(v.z); o.w=f2h(v.w); return o;
}
__device__ __forceinline__ f16x8 cvt8(float4 a, float4 b){
  f16x8 r;
  r[0]=(_Float16)a.x; r[1]=(_Float16)a.y; r[2]=(_Float16)a.z; r[3]=(_Float16)a.w;
  r[4]=(_Float16)b.x; r[5]=(_Float16)b.y; r[6]=(_Float16)b.z; r[7]=(_Float16)b.w;
  return r;
}
__device__ __forceinline__ f16x8 vscale(f16x8 v, _Float16 s){
  f16x8 r;
  #pragma unroll
  for (int i=0;i<8;i++) r[i] = v[i]*s;
  return r;
}

// ---------------------------------------------------------------------------
// Prep kernel (merged):
//  blocks 0..127 : convert w_h, w_r (f32 [1024][128]) -> f16 fragment image
//                  w16[h][kq][n][8] (kq = i>>3); B-frags become 16-lane-
//                  contiguous 16B global reads (L2-resident).
//  blocks 128..191: CW[n][i] = sum_d k[kk][d]*w[h*128+d][i], n=h*32+kk,
//                  output f16 image [kq][256 n][8].
// ---------------------------------------------------------------------------
__global__ void prep_kernel(const float* __restrict__ wh, const float* __restrict__ wr,
                            const float* __restrict__ kh, const float* __restrict__ kr,
                            ushort* __restrict__ w16h, ushort* __restrict__ w16r,
                            ushort* __restrict__ cwh,  ushort* __restrict__ cwr){
  if (blockIdx.x < 128){
    int t = blockIdx.x * 256 + threadIdx.x;   // 0..32767
    int R  = t >> 5;          // global row 0..1023
    int c4 = t & 31;          // float4 index within row
    int h  = R >> 7, np = R & 127;
    int kq = c4 >> 1, pos = (c4 & 1) * 4;
    int dst = ((h*16 + kq)*128 + np)*8 + pos;
    float4 a = ((const float4*)wh)[t];
    *(ushort4*)&w16h[dst] = f4h(a);
    float4 b = ((const float4*)wr)[t];
    *(ushort4*)&w16r[dst] = f4h(b);
    return;
  }
  int bid = blockIdx.x - 128;                 // 0..63
  int m  = bid >> 5;
  int h  = (bid >> 2) & 7;
  int iq = bid & 3;
  const float* w = m ? wr : wh;
  const float* k = m ? kr : kh;
  ushort* cw = m ? cwr : cwh;

  extern __shared__ char smem[];
  float* w_s = (float*)smem;        // [128 d][32 i_local]
  float* k_s = w_s + 128*32;        // [32 kk][128 d]
  int t = threadIdx.x;

  #pragma unroll
  for (int p=0;p<4;p++){
    int f = t + p*256;
    int d = f >> 3, c4 = f & 7;
    *(float4*)&w_s[d*32 + c4*4] =
        *(const float4*)&w[(size_t)(h*128 + d)*128 + iq*32 + c4*4];
  }
  #pragma unroll
  for (int p=0;p<4;p++){
    int f = t + p*256;
    ((float4*)k_s)[f] = ((const float4*)k)[f];
  }
  __syncthreads();

  int il  = t & 31;
  int kk0 = t >> 5;
  float acc[4] = {0.f,0.f,0.f,0.f};
  for (int d=0; d<128; d++){
    float wv = w_s[d*32 + il];
    #pragma unroll
    for (int j=0;j<4;j++) acc[j] += k_s[(kk0 + 8*j)*128 + d] * wv;
  }
  int i = iq*32 + il;
  #pragma unroll
  for (int j=0;j<4;j++){
    int n = h*32 + kk0 + 8*j;
    cw[(size_t)((i>>3)*256 + n)*8 + (i&7)] = f2h(acc[j]);
  }
}

// ---------------------------------------------------------------------------
// Kernel A (attn16): per 16-row tile.
//   HK/RK = X @ CW^T (B-frags direct from L2), scatter to LDS, softmax over
//   64 logits/elem, write h_x / r_x row/col sums (already /S) to workspace.
// 4096 blocks x 256 threads. LDS 37.4 KB -> 4 blocks/CU (50% occupancy).
// ---------------------------------------------------------------------------
__global__ __launch_bounds__(256,4) void attn16_kernel(
    const float* __restrict__ h_emb, const float* __restrict__ r_emb,
    const ushort* __restrict__ cwh,  const ushort* __restrict__ cwr,
    float* __restrict__ hx, float* __restrict__ rx)
{
  __shared__ float hk[16*292];      // [16 e][8 h][36] (stride 292 = 8*36+4)
  __shared__ float rk[16*292];

  const int t  = threadIdx.x;
  const int b0 = blockIdx.x * 16;
  const int l  = t & 63, w = t >> 6;
  const int g  = l >> 4, c = l & 15;

  // A fragments straight from global f32 (rows = c), convert to f16
  f16x8 ah[4], ar[4];
  {
    const float* ph = h_emb + ((size_t)(b0 + c))*128 + g*8;
    const float* pr = r_emb + ((size_t)(b0 + c))*128 + g*8;
    #pragma unroll
    for (int ks=0; ks<4; ks++){
      float4 lo  = *(const float4*)(ph + ks*32);
      float4 hi  = *(const float4*)(ph + ks*32 + 4);
      ah[ks] = cvt8(lo, hi);
      float4 lo2 = *(const float4*)(pr + ks*32);
      float4 hi2 = *(const float4*)(pr + ks*32 + 4);
      ar[ks] = cvt8(lo2, hi2);
    }
  }

  // HK/RK for n in [w*64, w*64+64)
  f32x4 aH[4] = {};
  f32x4 aR[4] = {};
  {
    const ushort* pH = cwh + ((size_t)(g*256 + w*64 + c))*8;
    const ushort* pR = cwr + ((size_t)(g*256 + w*64 + c))*8;
    #pragma unroll
    for (int ks=0; ks<4; ks++){
      #pragma unroll
      for (int nt=0; nt<4; nt++){
        f16x8 bh = *(const f16x8*)(pH + (size_t)(ks*1024 + nt*16)*8);
        f16x8 br = *(const f16x8*)(pR + (size_t)(ks*1024 + nt*16)*8);
        aH[nt] = __builtin_amdgcn_mfma_f32_16x16x32_f16(ah[ks], bh, aH[nt],0,0,0);
        aR[nt] = __builtin_amdgcn_mfma_f32_16x16x32_f16(ar[ks], br, aR[nt],0,0,0);
      }
    }
  }

  // scatter (C/D layout: col=lane&15, row=(lane>>4)*4+reg)
  #pragma unroll
  for (int nt=0; nt<4; nt++){
    int n  = w*64 + nt*16 + c;
    int hh = n >> 5, kk = n & 31;
    #pragma unroll
    for (int reg=0; reg<4; reg++){
      int e = g*4 + reg;
      hk[e*292 + hh*36 + kk] = aH[nt][reg];
      rk[e*292 + hh*36 + kk] = aR[nt][reg];
    }
  }
  __syncthreads();

  // softmax: thread = (element e, logit row hr), threads 0..127
  if (t < 128){
    int e = t >> 3, hr = t & 7;
    const float* hkr = &hk[e*292 + hr*36];
    float4 hv4[8];
    #pragma unroll
    for (int q=0;q<8;q++) hv4[q] = *(const float4*)&hkr[q*4];

    float lg[8];
    #pragma unroll
    for (int j=0;j<8;j++){
      const float* rkr = &rk[e*292 + j*36];
      float s = 0.f;
      #pragma unroll
      for (int q=0;q<8;q++){
        float4 rv = *(const float4*)&rkr[q*4];
        s += hv4[q].x*rv.x + hv4[q].y*rv.y + hv4[q].z*rv.z + hv4[q].w*rv.w;
      }
      lg[j] = s * TEMP_INV;
    }
    float mx = lg[0];
    #pragma unroll
    for (int j=1;j<8;j++) mx = fmaxf(mx, lg[j]);
    mx = fmaxf(mx, __shfl_xor(mx, 1));
    mx = fmaxf(mx, __shfl_xor(mx, 2));
    mx = fmaxf(mx, __shfl_xor(mx, 4));
    float p[8]; float srow = 0.f;
    #pragma unroll
    for (int j=0;j<8;j++){ p[j] = __expf(lg[j]-mx); srow += p[j]; }
    float S = srow;
    S += __shfl_xor(S, 1); S += __shfl_xor(S, 2); S += __shfl_xor(S, 4);
    float inv = 1.0f / S;
    hx[(size_t)(b0+e)*8 + hr] = srow * inv;

    #pragma unroll
    for (int j=0;j<8;j++){
      p[j] += __shfl_xor(p[j], 1);
      p[j] += __shfl_xor(p[j], 2);
      p[j] += __shfl_xor(p[j], 4);
    }
    float cs = p[0];
    #pragma unroll
    for (int j=1;j<8;j++) cs = (hr==j) ? p[j] : cs;
    rx[(size_t)(b0+e)*8 + hr] = cs * inv;
  }
}

// ---------------------------------------------------------------------------
// Kernel B (proj64): per 64-row tile, 4 waves x 32-col windows.
//   tacc = sum_h (hv.X_h)@Wh^T  (H-pass), then += sum_h (rv.X_r)@Wr^T
//   (R-pass, A registers reused). B-frags direct from L2, 1 KB load feeds
//   4 MFMAs. Then +residual, LayerNorm, store. LDS 8 KB; VGPR-bound occ.
// 1024 blocks x 256 threads.
// ---------------------------------------------------------------------------
__global__ __launch_bounds__(256,3) void proj64_kernel(
    const float* __restrict__ h_emb, const float* __restrict__ r_emb,
    const ushort* __restrict__ w16h, const ushort* __restrict__ w16r,
    const float* __restrict__ hx, const float* __restrict__ rx,
    const float* __restrict__ gamma, const float* __restrict__ beta,
    float* __restrict__ out)
{
  __shared__ float hxs[64*12];      // row-stride 12 (16B-aligned, low conflict)
  __shared__ float rxs[64*12];
  __shared__ float red[64*8];

  const int t  = threadIdx.x;
  const int b0 = blockIdx.x * 64;
  const int l  = t & 63, w = t >> 6;
  const int g  = l >> 4, c = l & 15;
  const int col0 = w*32;

  // stage h_x / r_x (each 512 f32) into padded LDS
  if (t < 128){
    float4 v = ((const float4*)(hx + (size_t)b0*8))[t];
    *(float4*)&hxs[(t>>1)*12 + (t&1)*4] = v;
  } else {
    int t2 = t - 128;
    float4 v = ((const float4*)(rx + (size_t)b0*8))[t2];
    *(float4*)&rxs[(t2>>1)*12 + (t2&1)*4] = v;
  }
  __syncthreads();

  f32x4 tacc[4][2] = {};
  f16x8 xa[4][4];                   // A-frags for the current pass

  #pragma unroll
  for (int pass=0; pass<2; pass++){
    const float*  xsrc = pass ? r_emb : h_emb;
    const ushort* wsrc = pass ? w16r  : w16h;
    const float*  ssrc = pass ? rxs   : hxs;

    // load A fragments for this pass (64 rows x 128 k, f32 -> f16)
    #pragma unroll
    for (int rf=0; rf<4; rf++){
      const float* p = xsrc + ((size_t)(b0 + rf*16 + c))*128 + g*8;
      #pragma unroll
      for (int ks=0; ks<4; ks++){
        float4 lo = *(const float4*)(p + ks*32);
        float4 hi = *(const float4*)(p + ks*32 + 4);
        xa[rf][ks] = cvt8(lo, hi);
      }
    }

    const ushort* bW = wsrc + ((size_t)(g*128 + col0 + c))*8;
    #pragma unroll
    for (int h=0; h<8; h++){
      _Float16 sc0 = (_Float16)ssrc[(     c)*12 + h];
      _Float16 sc1 = (_Float16)ssrc[(16 + c)*12 + h];
      _Float16 sc2 = (_Float16)ssrc[(32 + c)*12 + h];
      _Float16 sc3 = (_Float16)ssrc[(48 + c)*12 + h];
      #pragma unroll
      for (int ks=0; ks<4; ks++){
        size_t off = (size_t)((h*16 + ks*4)*128)*8;
        f16x8 b0v = *(const f16x8*)(bW + off);
        f16x8 b1v = *(const f16x8*)(bW + off + 16*8);
        f16x8 a0 = vscale(xa[0][ks], sc0);
        tacc[0][0] = __builtin_amdgcn_mfma_f32_16x16x32_f16(a0, b0v, tacc[0][0],0,0,0);
        tacc[0][1] = __builtin_amdgcn_mfma_f32_16x16x32_f16(a0, b1v, tacc[0][1],0,0,0);
        f16x8 a1 = vscale(xa[1][ks], sc1);
        tacc[1][0] = __builtin_amdgcn_mfma_f32_16x16x32_f16(a1, b0v, tacc[1][0],0,0,0);
        tacc[1][1] = __builtin_amdgcn_mfma_f32_16x16x32_f16(a1, b1v, tacc[1][1],0,0,0);
        f16x8 a2 = vscale(xa[2][ks], sc2);
        tacc[2][0] = __builtin_amdgcn_mfma_f32_16x16x32_f16(a2, b0v, tacc[2][0],0,0,0);
        tacc[2][1] = __builtin_amdgcn_mfma_f32_16x16x32_f16(a2, b1v, tacc[2][1],0,0,0);
        f16x8 a3 = vscale(xa[3][ks], sc3);
        tacc[3][0] = __builtin_amdgcn_mfma_f32_16x16x32_f16(a3, b0v, tacc[3][0],0,0,0);
        tacc[3][1] = __builtin_amdgcn_mfma_f32_16x16x32_f16(a3, b1v, tacc[3][1],0,0,0);
      }
    }
  }

  // residual
  #pragma unroll
  for (int rf=0; rf<4; rf++)
    #pragma unroll
    for (int reg=0; reg<4; reg++){
      int row = rf*16 + g*4 + reg;
      const float* resid = h_emb + ((size_t)(b0+row))*128 + col0 + c;
      tacc[rf][0][reg] += resid[0];
      tacc[rf][1][reg] += resid[16];
    }

  // LayerNorm row stats: butterfly over the 16 lanes of the col-window,
  // then combine the 4 waves' windows through LDS.
  #pragma unroll
  for (int rf=0; rf<4; rf++)
    #pragma unroll
    for (int reg=0; reg<4; reg++){
      float v0 = tacc[rf][0][reg], v1 = tacc[rf][1][reg];
      float a = v0 + v1, b2 = v0*v0 + v1*v1;
      #pragma unroll
      for (int m=1; m<16; m<<=1){
        a  += __shfl_xor(a,  m);
        b2 += __shfl_xor(b2, m);
      }
      if (c == 0){
        int row = rf*16 + g*4 + reg;
        red[row*8 + w*2]     = a;
        red[row*8 + w*2 + 1] = b2;
      }
    }
  __syncthreads();

  float gam0 = gamma[col0 + c],      bet0 = beta[col0 + c];
  float gam1 = gamma[col0 + 16 + c], bet1 = beta[col0 + 16 + c];
  #pragma unroll
  for (int rf=0; rf<4; rf++)
    #pragma unroll
    for (int reg=0; reg<4; reg++){
      int row = rf*16 + g*4 + reg;
      float S1 = red[row*8+0] + red[row*8+2] + red[row*8+4] + red[row*8+6];
      float S2 = red[row*8+1] + red[row*8+3] + red[row*8+5] + red[row*8+7];
      float mu  = S1 * 0.0078125f;             // /128
      float var = S2 * 0.0078125f - mu*mu;
      float rs  = rsqrtf(var + 1e-5f);
      float* po = out + ((size_t)(b0+row))*128 + col0 + c;
      po[0]  = gam0*((tacc[rf][0][reg]-mu)*rs) + bet0;
      po[16] = gam1*((tacc[rf][1][reg]-mu)*rs) + bet1;
    }
}

// ---------------------------------------------------------------------------
extern "C" void kernel_launch(void* const* d_in, const int* in_sizes, int n_in,
                              void* d_out, int out_size, void* d_ws, size_t ws_size,
                              hipStream_t stream){
  const float* h_emb = (const float*)d_in[0];
  const float* r_emb = (const float*)d_in[1];
  const float* w_h   = (const float*)d_in[2];
  const float* w_r   = (const float*)d_in[3];
  const float* k_h   = (const float*)d_in[4];
  const float* k_r   = (const float*)d_in[5];
  const float* gamma = (const float*)d_in[6];
  const float* beta  = (const float*)d_in[7];
  float* out = (float*)d_out;

  // workspace carve-up (~4.85 MB)
  ushort* w16h = (ushort*)d_ws;            // 1024*128 halves (fragment image)
  ushort* w16r = w16h + 131072;
  ushort* cwh  = w16r + 131072;            // 256*128 halves (fragment image)
  ushort* cwr  = cwh + 32768;
  float*  hxw  = (float*)(cwr + 32768);    // [B][8]
  float*  rxw  = hxw + 524288;

  prep_kernel<<<192, 256, 32768, stream>>>(w_h, w_r, k_h, k_r,
                                           w16h, w16r, cwh, cwr);
  attn16_kernel<<<4096, 256, 0, stream>>>(h_emb, r_emb, cwh, cwr, hxw, rxw);
  proj64_kernel<<<1024, 256, 0, stream>>>(h_emb, r_emb, w16h, w16r, hxw, rxw,
                                          gamma, beta, out);
}

// Round 5
// 215.631 us; speedup vs baseline: 1.0804x; 1.0804x over previous
//
#include <hip/hip_runtime.h>
#include <hip/hip_fp16.h>

// Problem constants (reference: N_HEAD=8, D_IN=128, D_KEY=32, B=65536)
#define TEMP_INV 0.17677669529663687f

typedef _Float16 f16x8 __attribute__((ext_vector_type(8)));
typedef float    f32x4 __attribute__((ext_vector_type(4)));

__device__ __forceinline__ ushort f2h(float x){
  __half h = __float2half(x);
  return __half_as_ushort(h);
}
__device__ __forceinline__ ushort4 f4h(float4 v){
  ushort4 o; o.x=f2h(v.x); o.y=f2h(v.y); o.z=f2h(v.z); o.w=f2h(v.w); return o;
}
__device__ __forceinline__ f16x8 cvt8(float4 a, float4 b){
  f16x8 r;
  r[0]=(_Float16)a.x; r[1]=(_Float16)a.y; r[2]=(_Float16)a.z; r[3]=(_Float16)a.w;
  r[4]=(_Float16)b.x; r[5]=(_Float16)b.y; r[6]=(_Float16)b.z; r[7]=(_Float16)b.w;
  return r;
}
__device__ __forceinline__ f16x8 vscale(f16x8 v, _Float16 s){
  f16x8 r;
  #pragma unroll
  for (int i=0;i<8;i++) r[i] = v[i]*s;
  return r;
}

// Async global->LDS: 16 KB chunk, 4 x global_load_lds_dwordx4 per thread.
// LDS dest is linear in thread order (wave-uniform base + lane*16 rule).
__device__ __forceinline__ void stage16k(const ushort* __restrict__ gsrc,
                                         ushort* lds, int t){
  typedef __attribute__((address_space(1))) const unsigned int guint;
  typedef __attribute__((address_space(3))) unsigned int luint;
  guint* g = (guint*)gsrc;
  luint* l = (luint*)lds;
  #pragma unroll
  for (int i=0;i<4;i++)
    __builtin_amdgcn_global_load_lds(g + t*4 + i*1024, l + t*4 + i*1024, 16, 0, 0);
}

// ---------------------------------------------------------------------------
// Prep kernel (merged):
//  blocks 0..127 : convert w_h, w_r (f32 [1024][128]) -> f16 fragment image
//                  w16[h][kq][n][8] (kq = i>>3).
//  blocks 128..191: CW[n][i] = sum_d k[kk][d]*w[h*128+d][i], n=h*32+kk,
//                  output f16 image [kq][256 n][8].
// ---------------------------------------------------------------------------
__global__ void prep_kernel(const float* __restrict__ wh, const float* __restrict__ wr,
                            const float* __restrict__ kh, const float* __restrict__ kr,
                            ushort* __restrict__ w16h, ushort* __restrict__ w16r,
                            ushort* __restrict__ cwh,  ushort* __restrict__ cwr){
  if (blockIdx.x < 128){
    int t = blockIdx.x * 256 + threadIdx.x;   // 0..32767
    int R  = t >> 5;          // global row 0..1023
    int c4 = t & 31;          // float4 index within row
    int h  = R >> 7, np = R & 127;
    int kq = c4 >> 1, pos = (c4 & 1) * 4;
    int dst = ((h*16 + kq)*128 + np)*8 + pos;
    float4 a = ((const float4*)wh)[t];
    *(ushort4*)&w16h[dst] = f4h(a);
    float4 b = ((const float4*)wr)[t];
    *(ushort4*)&w16r[dst] = f4h(b);
    return;
  }
  int bid = blockIdx.x - 128;                 // 0..63
  int m  = bid >> 5;
  int h  = (bid >> 2) & 7;
  int iq = bid & 3;
  const float* w = m ? wr : wh;
  const float* k = m ? kr : kh;
  ushort* cw = m ? cwr : cwh;

  extern __shared__ char smem[];
  float* w_s = (float*)smem;        // [128 d][32 i_local]
  float* k_s = w_s + 128*32;        // [32 kk][128 d]
  int t = threadIdx.x;

  #pragma unroll
  for (int p=0;p<4;p++){
    int f = t + p*256;
    int d = f >> 3, c4 = f & 7;
    *(float4*)&w_s[d*32 + c4*4] =
        *(const float4*)&w[(size_t)(h*128 + d)*128 + iq*32 + c4*4];
  }
  #pragma unroll
  for (int p=0;p<4;p++){
    int f = t + p*256;
    ((float4*)k_s)[f] = ((const float4*)k)[f];
  }
  __syncthreads();

  int il  = t & 31;
  int kk0 = t >> 5;
  float acc[4] = {0.f,0.f,0.f,0.f};
  for (int d=0; d<128; d++){
    float wv = w_s[d*32 + il];
    #pragma unroll
    for (int j=0;j<4;j++) acc[j] += k_s[(kk0 + 8*j)*128 + d] * wv;
  }
  int i = iq*32 + il;
  #pragma unroll
  for (int j=0;j<4;j++){
    int n = h*32 + kk0 + 8*j;
    cw[(size_t)((i>>3)*256 + n)*8 + (i&7)] = f2h(acc[j]);
  }
}

// ---------------------------------------------------------------------------
// Kernel A (attn16): per 16-row tile.
//   HK/RK = X @ CW^T (B-frags direct from L2), scatter to LDS, softmax over
//   64 logits/elem, write h_x / r_x row/col sums (already /S) to workspace.
// 4096 blocks x 256 threads. LDS 37.4 KB -> 4 blocks/CU.
// ---------------------------------------------------------------------------
__global__ __launch_bounds__(256,4) void attn16_kernel(
    const float* __restrict__ h_emb, const float* __restrict__ r_emb,
    const ushort* __restrict__ cwh,  const ushort* __restrict__ cwr,
    float* __restrict__ hx, float* __restrict__ rx)
{
  __shared__ float hk[16*292];      // [16 e][8 h][36] (stride 292 = 8*36+4)
  __shared__ float rk[16*292];

  const int t  = threadIdx.x;
  const int b0 = blockIdx.x * 16;
  const int l  = t & 63, w = t >> 6;
  const int g  = l >> 4, c = l & 15;

  // A fragments straight from global f32 (rows = c), convert to f16
  f16x8 ah[4], ar[4];
  {
    const float* ph = h_emb + ((size_t)(b0 + c))*128 + g*8;
    const float* pr = r_emb + ((size_t)(b0 + c))*128 + g*8;
    #pragma unroll
    for (int ks=0; ks<4; ks++){
      float4 lo  = *(const float4*)(ph + ks*32);
      float4 hi  = *(const float4*)(ph + ks*32 + 4);
      ah[ks] = cvt8(lo, hi);
      float4 lo2 = *(const float4*)(pr + ks*32);
      float4 hi2 = *(const float4*)(pr + ks*32 + 4);
      ar[ks] = cvt8(lo2, hi2);
    }
  }

  // HK/RK for n in [w*64, w*64+64)
  f32x4 aH[4] = {};
  f32x4 aR[4] = {};
  {
    const ushort* pH = cwh + ((size_t)(g*256 + w*64 + c))*8;
    const ushort* pR = cwr + ((size_t)(g*256 + w*64 + c))*8;
    #pragma unroll
    for (int ks=0; ks<4; ks++){
      #pragma unroll
      for (int nt=0; nt<4; nt++){
        f16x8 bh = *(const f16x8*)(pH + (size_t)(ks*1024 + nt*16)*8);
        f16x8 br = *(const f16x8*)(pR + (size_t)(ks*1024 + nt*16)*8);
        aH[nt] = __builtin_amdgcn_mfma_f32_16x16x32_f16(ah[ks], bh, aH[nt],0,0,0);
        aR[nt] = __builtin_amdgcn_mfma_f32_16x16x32_f16(ar[ks], br, aR[nt],0,0,0);
      }
    }
  }

  // scatter (C/D layout: col=lane&15, row=(lane>>4)*4+reg)
  #pragma unroll
  for (int nt=0; nt<4; nt++){
    int n  = w*64 + nt*16 + c;
    int hh = n >> 5, kk = n & 31;
    #pragma unroll
    for (int reg=0; reg<4; reg++){
      int e = g*4 + reg;
      hk[e*292 + hh*36 + kk] = aH[nt][reg];
      rk[e*292 + hh*36 + kk] = aR[nt][reg];
    }
  }
  __syncthreads();

  // softmax: thread = (element e, logit row hr), threads 0..127
  if (t < 128){
    int e = t >> 3, hr = t & 7;
    const float* hkr = &hk[e*292 + hr*36];
    float4 hv4[8];
    #pragma unroll
    for (int q=0;q<8;q++) hv4[q] = *(const float4*)&hkr[q*4];

    float lg[8];
    #pragma unroll
    for (int j=0;j<8;j++){
      const float* rkr = &rk[e*292 + j*36];
      float s = 0.f;
      #pragma unroll
      for (int q=0;q<8;q++){
        float4 rv = *(const float4*)&rkr[q*4];
        s += hv4[q].x*rv.x + hv4[q].y*rv.y + hv4[q].z*rv.z + hv4[q].w*rv.w;
      }
      lg[j] = s * TEMP_INV;
    }
    float mx = lg[0];
    #pragma unroll
    for (int j=1;j<8;j++) mx = fmaxf(mx, lg[j]);
    mx = fmaxf(mx, __shfl_xor(mx, 1));
    mx = fmaxf(mx, __shfl_xor(mx, 2));
    mx = fmaxf(mx, __shfl_xor(mx, 4));
    float p[8]; float srow = 0.f;
    #pragma unroll
    for (int j=0;j<8;j++){ p[j] = __expf(lg[j]-mx); srow += p[j]; }
    float S = srow;
    S += __shfl_xor(S, 1); S += __shfl_xor(S, 2); S += __shfl_xor(S, 4);
    float inv = 1.0f / S;
    hx[(size_t)(b0+e)*8 + hr] = srow * inv;

    #pragma unroll
    for (int j=0;j<8;j++){
      p[j] += __shfl_xor(p[j], 1);
      p[j] += __shfl_xor(p[j], 2);
      p[j] += __shfl_xor(p[j], 4);
    }
    float cs = p[0];
    #pragma unroll
    for (int j=1;j<8;j++) cs = (hr==j) ? p[j] : cs;
    rx[(size_t)(b0+e)*8 + hr] = cs * inv;
  }
}

// ---------------------------------------------------------------------------
// Kernel B (proj): per 64-row tile, 4 waves (2 M x 2 N), m97-style 2-barrier
// K-loop. Weights double-buffered in LDS via global_load_lds (16 KB chunks,
// chunk = one (matrix, head, K-half)); STAGE(next) issued before compute so
// latency hides under the previous chunk's 16 MFMAs. All-H then all-R passes
// so only one X matrix (32 VGPR) is live at a time; A pre-scaled by hv/rv.
// Epilogue: +residual, LayerNorm, store. 1024 blocks x 256 threads.
// LDS ~39 KB; target 3 blocks/CU.
// ---------------------------------------------------------------------------
__global__ __launch_bounds__(256,3) void proj_kernel(
    const float* __restrict__ h_emb, const float* __restrict__ r_emb,
    const ushort* __restrict__ w16h, const ushort* __restrict__ w16r,
    const float* __restrict__ hx, const float* __restrict__ rx,
    const float* __restrict__ gamma, const float* __restrict__ beta,
    float* __restrict__ out)
{
  __shared__ ushort wbuf[2][8192];  // 2 x 16 KB weight chunks [8 kq][128 n][8]
  __shared__ float hxs[64*12];      // row-stride 12 (16B-aligned stores)
  __shared__ float rxs[64*12];
  __shared__ float red[64*4];

  const int t  = threadIdx.x;
  const int b0 = blockIdx.x * 64;
  const int l  = t & 63, w = t >> 6;
  const int g  = l >> 4, c = l & 15;
  const int wm = w & 1, wn = w >> 1;   // wave: rows wm*32..+32, cols wn*64..+64

  // stage h_x / r_x (each 512 f32) into padded LDS
  if (t < 128){
    float4 v = ((const float4*)(hx + (size_t)b0*8))[t];
    *(float4*)&hxs[(t>>1)*12 + (t&1)*4] = v;
  } else {
    int t2 = t - 128;
    float4 v = ((const float4*)(rx + (size_t)b0*8))[t2];
    *(float4*)&rxs[(t2>>1)*12 + (t2&1)*4] = v;
  }

  // prologue: stage first chunk (H, h=0, khalf=0) into buf 0
  stage16k(w16h, &wbuf[0][0], t);
  __syncthreads();   // hxs/rxs + first chunk ready

  f32x4 tacc[2][4] = {};   // [mt][nt]

  #pragma unroll
  for (int pass=0; pass<2; pass++){
    const float*  xs = pass ? r_emb : h_emb;
    const ushort* ws = pass ? w16r  : w16h;
    const float*  sc = pass ? rxs   : hxs;

    // X fragments for this pass: rows wm*32 + mt*16 + c, k = ks*32 + g*8
    f16x8 xa[2][4];
    #pragma unroll
    for (int mt=0; mt<2; mt++){
      const float* p = xs + ((size_t)(b0 + wm*32 + mt*16 + c))*128 + g*8;
      #pragma unroll
      for (int ks=0; ks<4; ks++){
        float4 lo = *(const float4*)(p + ks*32);
        float4 hi = *(const float4*)(p + ks*32 + 4);
        xa[mt][ks] = cvt8(lo, hi);
      }
    }

    for (int h=0; h<8; h++){
      _Float16 s0 = (_Float16)sc[(wm*32 +      c)*12 + h];
      _Float16 s1 = (_Float16)sc[(wm*32 + 16 + c)*12 + h];
      f16x8 a0[4], a1[4];
      #pragma unroll
      for (int ks=0; ks<4; ks++){
        a0[ks] = vscale(xa[0][ks], s0);
        a1[ks] = vscale(xa[1][ks], s1);
      }
      #pragma unroll
      for (int kh=0; kh<2; kh++){
        // stage next chunk into the other buffer (skip on the very last)
        if (!(pass==1 && h==7 && kh==1)){
          const ushort* nsrc;
          if (kh == 0)      nsrc = ws + (size_t)(h*16 + 8)*1024;
          else if (h < 7)   nsrc = ws + (size_t)((h+1)*16)*1024;
          else              nsrc = w16r;          // pass0,h7 -> pass1 start
          stage16k(nsrc, &wbuf[kh^1][0], t);
        }
        // compute from wbuf[kh] (already resident)
        const ushort* bb = &wbuf[kh][0] + (size_t)(g*128 + wn*64 + c)*8;
        #pragma unroll
        for (int ks2=0; ks2<2; ks2++){
          int ks = kh*2 + ks2;
          #pragma unroll
          for (int nt=0; nt<4; nt++){
            f16x8 bv = *(const f16x8*)(bb + ks2*4096 + nt*128);
            tacc[0][nt] = __builtin_amdgcn_mfma_f32_16x16x32_f16(a0[ks], bv, tacc[0][nt],0,0,0);
            tacc[1][nt] = __builtin_amdgcn_mfma_f32_16x16x32_f16(a1[ks], bv, tacc[1][nt],0,0,0);
          }
        }
        // one barrier per chunk: drains staging (vmcnt) + guards ds reads
        __syncthreads();
      }
    }
  }

  // ---- residual ---------------------------------------------------------
  #pragma unroll
  for (int mt=0; mt<2; mt++)
    #pragma unroll
    for (int reg=0; reg<4; reg++){
      int row = wm*32 + mt*16 + g*4 + reg;
      const float* resid = h_emb + ((size_t)(b0+row))*128 + wn*64 + c;
      #pragma unroll
      for (int nt=0; nt<4; nt++)
        tacc[mt][nt][reg] += resid[nt*16];
    }

  // ---- LayerNorm row stats ---------------------------------------------
  #pragma unroll
  for (int mt=0; mt<2; mt++)
    #pragma unroll
    for (int reg=0; reg<4; reg++){
      float a = 0.f, b2 = 0.f;
      #pragma unroll
      for (int nt=0; nt<4; nt++){
        float v = tacc[mt][nt][reg]; a += v; b2 += v*v;
      }
      #pragma unroll
      for (int m=1; m<16; m<<=1){
        a  += __shfl_xor(a,  m);
        b2 += __shfl_xor(b2, m);
      }
      if (c == 0){
        int row = wm*32 + mt*16 + g*4 + reg;
        red[row*4 + wn*2]     = a;
        red[row*4 + wn*2 + 1] = b2;
      }
    }
  __syncthreads();

  float gam[4], bet[4];
  #pragma unroll
  for (int nt=0; nt<4; nt++){
    gam[nt] = gamma[wn*64 + nt*16 + c];
    bet[nt] = beta [wn*64 + nt*16 + c];
  }
  #pragma unroll
  for (int mt=0; mt<2; mt++)
    #pragma unroll
    for (int reg=0; reg<4; reg++){
      int row = wm*32 + mt*16 + g*4 + reg;
      float S1 = red[row*4+0] + red[row*4+2];
      float S2 = red[row*4+1] + red[row*4+3];
      float mu  = S1 * 0.0078125f;             // /128
      float var = S2 * 0.0078125f - mu*mu;
      float rs  = rsqrtf(var + 1e-5f);
      float* po = out + ((size_t)(b0+row))*128 + wn*64 + c;
      #pragma unroll
      for (int nt=0; nt<4; nt++)
        po[nt*16] = gam[nt]*((tacc[mt][nt][reg]-mu)*rs) + bet[nt];
    }
}

// ---------------------------------------------------------------------------
extern "C" void kernel_launch(void* const* d_in, const int* in_sizes, int n_in,
                              void* d_out, int out_size, void* d_ws, size_t ws_size,
                              hipStream_t stream){
  const float* h_emb = (const float*)d_in[0];
  const float* r_emb = (const float*)d_in[1];
  const float* w_h   = (const float*)d_in[2];
  const float* w_r   = (const float*)d_in[3];
  const float* k_h   = (const float*)d_in[4];
  const float* k_r   = (const float*)d_in[5];
  const float* gamma = (const float*)d_in[6];
  const float* beta  = (const float*)d_in[7];
  float* out = (float*)d_out;

  // workspace carve-up (~4.85 MB)
  ushort* w16h = (ushort*)d_ws;            // 1024*128 halves (fragment image)
  ushort* w16r = w16h + 131072;
  ushort* cwh  = w16r + 131072;            // 256*128 halves (fragment image)
  ushort* cwr  = cwh + 32768;
  float*  hxw  = (float*)(cwr + 32768);    // [B][8]
  float*  rxw  = hxw + 524288;

  prep_kernel<<<192, 256, 32768, stream>>>(w_h, w_r, k_h, k_r,
                                           w16h, w16r, cwh, cwr);
  attn16_kernel<<<4096, 256, 0, stream>>>(h_emb, r_emb, cwh, cwr, hxw, rxw);
  proj_kernel<<<1024, 256, 0, stream>>>(h_emb, r_emb, w16h, w16r, hxw, rxw,
                                        gamma, beta, out);
}